// Round 3
// baseline (313.382 us; speedup 1.0000x reference)
//
#include <hip/hip_runtime.h>

// QuaternionLinear as GEMM: M=32768 (batch), N=1024 (OUT_F*4), K=1024 (IN_F*4).
// W_eff[4o+r][4i+c] = sign(r,c) * weight[o][i][r^c], built in d_ws as bf16.
//
// R6: R4 (8-phase, 86.7us) and R5 (quad, 90.8us) bracket the same plateau
// (MfmaUtil 30-32, VALU 15, HBM 28 — nothing saturated): barrier-count
// restructuring is refuted as the lever at 1 block/CU. The certain win left
// is traffic: the separate prep kernel round-trips x through HBM (128 MB read
// + 64 MB write ≈ 31us) only to have the GEMM re-read it. Fuse the fp32->bf16
// conversion INTO the R4 8-phase skeleton: A staged reg-wise (4x dwordx4 fp32
// issued 2 phases early -> counted vmcnt(6)/(4) -> cvt -> 2x ds_write_b128,
// bank-conflict-free swizzled write), B unchanged via global_load_lds with
// source-XOR. Mixed vmcnt ledger (A reg-loads + B DMA share the counter)
// verified phase-by-phase; in-flight 4..14, never drained to 0 in-loop.
// Eliminates prep entirely; d_ws needs only 2 MiB (W_eff).

typedef __bf16 bf16x8_t __attribute__((ext_vector_type(8)));
typedef short short8    __attribute__((ext_vector_type(8)));
typedef float f32x4     __attribute__((ext_vector_type(4)));
typedef float f32x8     __attribute__((ext_vector_type(8)));

typedef const unsigned int __attribute__((address_space(1)))* gas_uint_ptr;
typedef unsigned int __attribute__((address_space(3)))*       las_uint_ptr;

// ---------------------------------------------------------------------------
// Prep: build effective bf16 weight matrix W_eff (1024 x 1024), row n = 4o+r,
// col k = 4i+c.  Component select s = r^c; sign bit from table 0x284E.
// ---------------------------------------------------------------------------
__global__ __launch_bounds__(256) void build_weff(const float* __restrict__ w,
                                                  unsigned short* __restrict__ wq) {
    const int idx = blockIdx.x * 256 + threadIdx.x;   // 0 .. 1048575
    const int n = idx >> 10, k = idx & 1023;
    const int o = n >> 2, r = n & 3, i = k >> 2, cc = k & 3;
    const int s = r ^ cc;
    float v = w[o * 1024 + i * 4 + s];
    if ((0x284E >> (r * 4 + cc)) & 1) v = -v;
    union { __bf16 b; unsigned short u; } cv;
    cv.b = (__bf16)v;
    wq[idx] = cv.u;
}

// ---------------------------------------------------------------------------
// Fused-conversion 8-phase 256x256 GEMM. Grid = 512 blocks x 512 threads
// (8 waves, 2M x 4N). Per wave: 128x64 output = acc[8][4] f32x4. BK=64.
//
// LDS: As/Bs[par][half][128*64] bf16, 128 KiB. A-tile layout: 16B chunk g of
// row r lives at slot g^(r&7). B staged by global_load_lds (SOURCE-permuted,
// dest linear); A staged by this kernel's own swizzled ds_write_b128 (8
// lanes/row x 8 slots tile each 128B row => conflict-free).
//
// Per-iteration i (K-tiles 2i [par0, computed P1-P4] and 2i+1 [par1, P5-P8]):
//   P1: rdBF(0)+rdAF(0,0); LOAD_A(2i+1,h0)->rA0(4 ld)   | bar lgkm0 MFMA bar
//   P2: rdAF(0,1);         LOAD_A(2i+1,h1)->rA1(4 ld)   | ...
//   P3: rdAF(0,2); GB(2i+2,h0)(2); vmcnt(6); WRITE_A(2i+1,h0,rA0)
//   P4: rdAF(0,3); GB(2i+2,h1)(2); vmcnt(4); WRITE_A(2i+1,h1,rA1)
//       -> end-P4 barrier publishes tile 2i+1 (A ds-written + lgkm0'd by all
//          waves; B(2i+1) drained by every wave's P3 vmcnt(6))
//   P5-P8: symmetric for tile 2i+2.
// vmcnt ledger (per thread, issue order): entry B(2i+1)=4; P1 +4A=8; P2 +4A
//   =12; P3 +2B=14, vmcnt(6) drains B(2i+1)4+A_h0·4; P4 +2B=8, vmcnt(4)
//   drains A_h1·4 -> leaves B(2i+2)=4. Invariant restored. Never 0 in-loop.
// Buffer hazards: every ds_write/DMA target's last reads retired >=1
//   end-barrier earlier (reads retire at each wave's lgkm0 < its end-bar).
// Tail clamps (kt&15): harmless re-stage of tile-0/1 data into dead buffers.
// ---------------------------------------------------------------------------
__global__ __launch_bounds__(512, 2) void qlin_gemm_f32a(
        const float* __restrict__ Xf,
        const unsigned short* __restrict__ Wq,
        const float* __restrict__ bias,
        float* __restrict__ out) {
    __shared__ __align__(16) unsigned short As[2][2][128 * 64];   // 64 KiB
    __shared__ __align__(16) unsigned short Bs[2][2][128 * 64];   // 64 KiB

    const int t    = threadIdx.x;
    const int w    = t >> 6;
    const int l    = t & 63;
    const int lo16 = l & 15;
    const int hi2  = l >> 4;

    // A-staging lane mapping: 8 lanes per row, one 8-elem chunk each.
    const int rsub = t >> 3;                     // 0..63 (row, and row+64)
    const int g8   = t & 7;                      // chunk index
    const int sgA  = g8 ^ (rsub & 7);            // swizzled slot (same for row+64)

    const int bid     = blockIdx.x;
    const int xcd     = bid & 7;                 // HW round-robins XCDs
    const int logical = xcd * 64 + (bid >> 3);   // contiguous chunk per XCD
    const int m0      = (logical >> 2) * 256;    // 4 n-tiles share an A panel
    const int n0      = (logical & 3) * 256;

    const int wm  = (w >> 2) * 128;              // 0 / 128
    const int wn  = (w & 3) * 64;                // 0 / 64 / 128 / 192
    const int hA  = wm >> 7;                     // A half read by this wave
    const int hB  = wn >> 7;                     // B half read by this wave
    const int rbB = wn & 64;                     // B row base within half

    f32x4 acc[8][4] = {};
    short8 af[2][2];
    short8 bf[4][2];
    f32x4 rA0[4], rA1[4];                        // in-flight fp32 A (static idx)

    // lane-constant swizzled slot for k-slice ks: (ks*4 + hi2) ^ (lo16 & 7)
    const int sw    = lo16 & 7;
    const int slot0 = hi2 ^ sw;
    const int slot1 = (4 + hi2) ^ sw;

#define LOAD_A(KT, H, R) do {                                                   \
        const float* ga_ = Xf + ((long long)(m0 + (H) * 128 + rsub) << 10)      \
                              + (((KT) & 15) << 6) + (g8 << 3);                 \
        R[0] = *(const f32x4*)ga_;                                              \
        R[1] = *(const f32x4*)(ga_ + 4);                                        \
        R[2] = *(const f32x4*)(ga_ + 65536);     /* row + 64 */                 \
        R[3] = *(const f32x4*)(ga_ + 65540);                                    \
    } while (0)

#define WRITE_A(KT, H, R) do {                                                  \
        f32x8 lo_ = __builtin_shufflevector(R[0], R[1], 0, 1, 2, 3, 4, 5, 6, 7);\
        f32x8 hi_ = __builtin_shufflevector(R[2], R[3], 0, 1, 2, 3, 4, 5, 6, 7);\
        union { bf16x8_t b; short8 s; } c0_, c1_;                               \
        c0_.b = __builtin_convertvector(lo_, bf16x8_t);                         \
        c1_.b = __builtin_convertvector(hi_, bf16x8_t);                         \
        *(short8*)(&As[(KT) & 1][(H)][(rsub * 8 + sgA) * 8]) = c0_.s;           \
        *(short8*)(&As[(KT) & 1][(H)][((64 + rsub) * 8 + sgA) * 8]) = c1_.s;    \
    } while (0)

#define STAGE_B(KT, H) do {                                                     \
        const int kk_ = ((KT) & 15) * 64;                                       \
        _Pragma("unroll")                                                       \
        for (int jj = 0; jj < 2; ++jj) {                                        \
            const int idx_ = jj * 512 + t;                                      \
            const int row_ = idx_ >> 3;                                         \
            const int g_   = (idx_ & 7) ^ (row_ & 7);                           \
            const unsigned short* gb_ =                                         \
                Wq + (n0 + (H) * 128 + row_) * 1024 + kk_ + g_ * 8;             \
            __builtin_amdgcn_global_load_lds((gas_uint_ptr)gb_,                 \
                (las_uint_ptr)(&Bs[(KT) & 1][(H)][idx_ * 8]), 16, 0, 0);        \
        }                                                                       \
    } while (0)

#define READ_BF(PAR) do {                                                       \
        _Pragma("unroll")                                                       \
        for (int nt = 0; nt < 4; ++nt) {                                        \
            const int rl_ = rbB + nt * 16 + lo16;                               \
            bf[nt][0] = *(const short8*)(&Bs[(PAR)][hB][rl_ * 64 + slot0 * 8]); \
            bf[nt][1] = *(const short8*)(&Bs[(PAR)][hB][rl_ * 64 + slot1 * 8]); \
        }                                                                       \
    } while (0)

#define READ_AF(PAR, MTB) do {                                                  \
        _Pragma("unroll")                                                       \
        for (int mi = 0; mi < 2; ++mi) {                                        \
            const int rl_ = ((MTB) + mi) * 16 + lo16;                           \
            af[mi][0] = *(const short8*)(&As[(PAR)][hA][rl_ * 64 + slot0 * 8]); \
            af[mi][1] = *(const short8*)(&As[(PAR)][hA][rl_ * 64 + slot1 * 8]); \
        }                                                                       \
    } while (0)

#define MFMA_H(MTB) do {                                                        \
        _Pragma("unroll")                                                       \
        for (int mi = 0; mi < 2; ++mi)                                          \
            _Pragma("unroll")                                                   \
            for (int nt = 0; nt < 4; ++nt) {                                    \
                acc[(MTB) + mi][nt] = __builtin_amdgcn_mfma_f32_16x16x32_bf16(  \
                    af[mi][0], bf[nt][0], acc[(MTB) + mi][nt], 0, 0, 0);        \
                acc[(MTB) + mi][nt] = __builtin_amdgcn_mfma_f32_16x16x32_bf16(  \
                    af[mi][1], bf[nt][1], acc[(MTB) + mi][nt], 0, 0, 0);        \
            }                                                                   \
    } while (0)

#define BAR()   asm volatile("s_barrier" ::: "memory")
#define LGKM0() asm volatile("s_waitcnt lgkmcnt(0)" ::: "memory")

#define PHASE_TAIL(MTB) do {                                                    \
        BAR(); LGKM0();                                                         \
        __builtin_amdgcn_s_setprio(1);                                          \
        MFMA_H(MTB);                                                            \
        __builtin_amdgcn_s_setprio(0);                                          \
        BAR();                                                                  \
    } while (0)

    // Prologue: B(0) DMA [4], A(0) reg-loads [8->12], B(1) DMA [->16];
    // vmcnt(4) drains B(0)+A(0)-loads, leaves B(1)=4; write A(0); publish.
    STAGE_B(0, 0); STAGE_B(0, 1);
    LOAD_A(0, 0, rA0);
    LOAD_A(0, 1, rA1);
    STAGE_B(1, 0); STAGE_B(1, 1);
    asm volatile("s_waitcnt vmcnt(4)" ::: "memory");
    WRITE_A(0, 0, rA0);
    WRITE_A(0, 1, rA1);
    LGKM0();
    BAR();                                        // publish tile 0

    for (int i = 0; i < 8; ++i) {
        const int kt1 = 2 * i + 1;

        // ---- tile 2i (par 0) ----
        READ_BF(0); READ_AF(0, 0);
        LOAD_A(kt1, 0, rA0);                      // P1
        PHASE_TAIL(0);

        READ_AF(0, 2);
        LOAD_A(kt1, 1, rA1);                      // P2
        PHASE_TAIL(2);

        READ_AF(0, 4);
        STAGE_B(kt1 + 1, 0);                      // P3
        asm volatile("s_waitcnt vmcnt(6)" ::: "memory");
        WRITE_A(kt1, 0, rA0);
        PHASE_TAIL(4);

        READ_AF(0, 6);
        STAGE_B(kt1 + 1, 1);                      // P4
        asm volatile("s_waitcnt vmcnt(4)" ::: "memory");
        WRITE_A(kt1, 1, rA1);
        PHASE_TAIL(6);                            // end-bar publishes tile 2i+1

        // ---- tile 2i+1 (par 1) ----
        READ_BF(1); READ_AF(1, 0);
        LOAD_A(kt1 + 1, 0, rA0);                  // P5
        PHASE_TAIL(0);

        READ_AF(1, 2);
        LOAD_A(kt1 + 1, 1, rA1);                  // P6
        PHASE_TAIL(2);

        READ_AF(1, 4);
        STAGE_B(kt1 + 2, 0);                      // P7
        asm volatile("s_waitcnt vmcnt(6)" ::: "memory");
        WRITE_A(kt1 + 1, 0, rA0);
        PHASE_TAIL(4);

        READ_AF(1, 6);
        STAGE_B(kt1 + 2, 1);                      // P8
        asm volatile("s_waitcnt vmcnt(4)" ::: "memory");
        WRITE_A(kt1 + 1, 1, rA1);
        PHASE_TAIL(6);                            // end-bar publishes tile 2i+2
    }
    asm volatile("s_waitcnt vmcnt(0)" ::: "memory"); // no DMA past wave exit

#undef LOAD_A
#undef WRITE_A
#undef STAGE_B
#undef READ_BF
#undef READ_AF
#undef MFMA_H
#undef BAR
#undef LGKM0
#undef PHASE_TAIL

    // Epilogue: C/D layout col(n) = lane&15, row(m) = (lane>>4)*4 + reg.
#pragma unroll
    for (int nt = 0; nt < 4; ++nt) {
        const int n  = n0 + wn + nt * 16 + lo16;
        const float bv = bias[n];
#pragma unroll
        for (int mt = 0; mt < 8; ++mt) {
            const int mb = m0 + wm + mt * 16 + hi2 * 4;
#pragma unroll
            for (int r = 0; r < 4; ++r)
                out[(long long)(mb + r) * 1024 + n] = acc[mt][nt][r] + bv;
        }
    }
}

// ---------------------------------------------------------------------------
extern "C" void kernel_launch(void* const* d_in, const int* in_sizes, int n_in,
                              void* d_out, int out_size, void* d_ws, size_t ws_size,
                              hipStream_t stream) {
    const float* x  = (const float*)d_in[0];   // (32768, 256, 4) fp32
    const float* wt = (const float*)d_in[1];   // (256, 256, 4) fp32
    const float* bs = (const float*)d_in[2];   // (256, 4) fp32
    float* out = (float*)d_out;                // (32768, 256, 4) fp32

    unsigned short* wq = (unsigned short*)d_ws;            // 2 MiB W_eff bf16

    build_weff<<<4096, 256, 0, stream>>>(wt, wq);
    qlin_gemm_f32a<<<512, 512, 0, stream>>>(x, wq, bs, out);

    (void)in_sizes; (void)n_in; (void)out_size; (void)ws_size;
}